// Round 6
// baseline (119.632 us; speedup 1.0000x reference)
//
#include <hip/hip_runtime.h>

typedef unsigned short u16;
typedef __bf16 bf16x8 __attribute__((ext_vector_type(8)));
typedef float f32x4 __attribute__((ext_vector_type(4)));
typedef u16 u16x8 __attribute__((ext_vector_type(8)));

#define KSPLIT 4             // qkv GEMM K-splits
#define KC 1024              // 4096 / KSPLIT
#define NKT 16               // KC / 64
#define OSPLIT 8             // oproj K-splits (512 each, 8 steps of 64)
#define SCALE_Q 0.08838834764831843f   // 1/sqrt(128), folded into q

__device__ __forceinline__ u16 f2bf(float f) {
    unsigned u = __builtin_bit_cast(unsigned, f);
    u += 0x7fff + ((u >> 16) & 1);     // RNE
    return (u16)(u >> 16);
}
__device__ __forceinline__ float bf2f(u16 h) {
    unsigned u = ((unsigned)h) << 16;
    return __builtin_bit_cast(float, u);
}
__device__ __forceinline__ f32x4 mfma16(bf16x8 a, bf16x8 b, f32x4 c) {
    return __builtin_amdgcn_mfma_f32_16x16x32_bf16(a, b, c, 0, 0, 0);
}

// ------ Kernel 0: pre-pack c=[x_ctx;x] as bf16 MFMA A-fragments (1 MB) ------
// fragA[((ks32*8 + rt)*64 + l)*8 + e] = bf16(c[rt*16 + (l&15)][ks32*32 + (l>>4)*8 + e])
__global__ __launch_bounds__(256)
void k_prep(const float* __restrict__ x, const float* __restrict__ xctx,
            u16* __restrict__ fragA)
{
    int tid = blockIdx.x * 256 + threadIdx.x;   // 65536 threads
    int row = tid >> 9;                         // 0..127
    int kc = tid & 511;                         // k-chunk of 8
    int k0 = kc << 3;
    const float* src = (row < 64) ? (xctx + (size_t)row * 4096)
                                  : (x + (size_t)(row - 64) * 4096);
    f32x4 v0 = *(const f32x4*)&src[k0];
    f32x4 v1 = *(const f32x4*)&src[k0 + 4];
    u16x8 o;
    o[0] = f2bf(v0[0]); o[1] = f2bf(v0[1]); o[2] = f2bf(v0[2]); o[3] = f2bf(v0[3]);
    o[4] = f2bf(v1[0]); o[5] = f2bf(v1[1]); o[6] = f2bf(v1[2]); o[7] = f2bf(v1[3]);
    int ks32 = k0 >> 5;
    int lg = (k0 >> 3) & 3;
    int rt = row >> 4;
    int l = lg * 16 + (row & 15);
    *(u16x8*)&fragA[(((size_t)ks32 * 8 + rt) * 64 + l) * 8] = o;
}

// ---------------- Kernel 1: QKV projection, split-K streaming ---------------
// grid (384, KSPLIT): x = 16-col tile over [Wq(4096)|Wk(1024)|Wv(1024)],
// y = K-split of 1024. 1536 blocks (~6/CU). A from fragA (global->reg);
// only B staged (2 KB swizzled LDS). Writes f32 partials part[ksp][128][6144].
__global__ __launch_bounds__(256)
void k_qkv(const u16* __restrict__ fragA,
           const float* __restrict__ Wq, const float* __restrict__ Wk,
           const float* __restrict__ Wv, float* __restrict__ part)
{
    const int col0 = blockIdx.x * 16;
    const int ksp = blockIdx.y;
    const int ks0 = ksp * KC;
    const float* W; int ldw, cbase, mat;
    if (col0 < 4096)      { W = Wq; ldw = 4096; cbase = col0;        mat = 0; }
    else if (col0 < 5120) { W = Wk; ldw = 1024; cbase = col0 - 4096; mat = 1; }
    else                  { W = Wv; ldw = 1024; cbase = col0 - 5120; mat = 2; }
    const bool full = (mat != 0);          // k/v need all 128 rows; q only x rows
    const int rowbase = full ? 0 : 64;

    __shared__ __align__(16) u16 Bs[16 * 64];   // [n][k] with XOR swizzle, 2KB

    const int t = threadIdx.x;
    const int w = t >> 6, l = t & 63;
    const int lm = l & 15, lg = l >> 4;

    const int bkk = t >> 2;                // k row 0..63
    const int bn4 = (t & 3) << 2;          // col group of 4

    f32x4 pb;
    f32x4 acc[2] = {};

    const int rt0 = full ? (w * 2) : (4 + w);  // A row-tile(s) for this wave

    #define QKV_BLOAD(kt_)                                                     \
        pb = *(const f32x4*)&W[(size_t)(ks0 + (kt_) * 64 + bkk) * ldw + cbase + bn4];

    #define QKV_BSTORE()                                                       \
    {                                                                          \
        _Pragma("unroll")                                                      \
        for (int j = 0; j < 4; j++) {                                          \
            int n = bn4 + j;                                                   \
            Bs[n * 64 + (bkk ^ (((n >> 1) & 7) << 3))] = f2bf(pb[j]);          \
        }                                                                      \
    }

    QKV_BLOAD(0);
    #pragma unroll 1
    for (int kt = 0; kt < NKT; kt++) {
        if (kt) __syncthreads();           // prev tile's readers done
        QKV_BSTORE();
        __syncthreads();
        if (kt + 1 < NKT) QKV_BLOAD(kt + 1);
        const int ks32b = (ks0 >> 5) + kt * 2;
        #pragma unroll
        for (int ks = 0; ks < 2; ks++) {
            const int koff = ks * 32 + lg * 8;
            bf16x8 b = *(const bf16x8*)&Bs[lm * 64 + (koff ^ (((lm >> 1) & 7) << 3))];
            bf16x8 a0 = *(const bf16x8*)
                &fragA[(((size_t)(ks32b + ks) * 8 + rt0) * 64 + l) * 8];
            acc[0] = mfma16(a0, b, acc[0]);
            if (full) {
                bf16x8 a1 = *(const bf16x8*)
                    &fragA[(((size_t)(ks32b + ks) * 8 + rt0 + 1) * 64 + l) * 8];
                acc[1] = mfma16(a1, b, acc[1]);
            }
        }
    }

    const int wrows = full ? 32 : 16;
    const int mts = full ? 2 : 1;
    #pragma unroll
    for (int mt = 0; mt < 2; mt++) {
        if (mt >= mts) break;
        #pragma unroll
        for (int r = 0; r < 4; r++) {
            int grow = rowbase + w * wrows + mt * 16 + lg * 4 + r;
            part[((size_t)ksp * 128 + grow) * 6144 + col0 + lm] = acc[mt][r];
        }
    }
    #undef QKV_BLOAD
    #undef QKV_BSTORE
}

// ------- Kernel 2: partial-sum + RMSNorm + RoPE (q, k) + v passthrough ------
__global__ __launch_bounds__(256)
void k_normrope(const float* __restrict__ part,
                const float* __restrict__ cosq, const float* __restrict__ sinq,
                const float* __restrict__ cosk, const float* __restrict__ sink,
                const float* __restrict__ qnw, const float* __restrict__ knw,
                u16* __restrict__ qb, u16* __restrict__ kb,
                float* __restrict__ outk, float* __restrict__ outv,
                u16* __restrict__ vbw)
{
    int wid = blockIdx.x * 4 + (threadIdx.x >> 6);
    int lane = threadIdx.x & 63;
    if (wid < 2048) {                          // q: (h, l)
        int h = wid >> 6, lq = wid & 63;
        size_t ro = (size_t)(64 + lq) * 6144 + h * 128;
        float x1 = 0.f, x2 = 0.f;
        #pragma unroll
        for (int s = 0; s < KSPLIT; s++) {
            x1 += part[(size_t)s * 786432 + ro + lane];
            x2 += part[(size_t)s * 786432 + ro + lane + 64];
        }
        float ss = x1 * x1 + x2 * x2;
        #pragma unroll
        for (int off = 32; off; off >>= 1) ss += __shfl_xor(ss, off);
        float rms = rsqrtf(ss * (1.0f / 128.0f) + 1e-6f);
        float a = x1 * rms * qnw[lane];
        float b = x2 * rms * qnw[lane + 64];
        float c = cosq[lq * 64 + lane], s = sinq[lq * 64 + lane];
        u16* qo = qb + ((size_t)h * 64 + lq) * 128;
        qo[lane]      = f2bf((a * c - b * s) * SCALE_Q);
        qo[lane + 64] = f2bf((b * c + a * s) * SCALE_Q);
    } else if (wid < 3072) {                   // k: (kh, t)
        int rr = wid - 2048;
        int kh = rr >> 7, tt = rr & 127;
        size_t ro = (size_t)tt * 6144 + 4096 + kh * 128;
        float x1 = 0.f, x2 = 0.f;
        #pragma unroll
        for (int s = 0; s < KSPLIT; s++) {
            x1 += part[(size_t)s * 786432 + ro + lane];
            x2 += part[(size_t)s * 786432 + ro + lane + 64];
        }
        float ss = x1 * x1 + x2 * x2;
        #pragma unroll
        for (int off = 32; off; off >>= 1) ss += __shfl_xor(ss, off);
        float rms = rsqrtf(ss * (1.0f / 128.0f) + 1e-6f);
        float a = x1 * rms * knw[lane];
        float b = x2 * rms * knw[lane + 64];
        float c = cosk[tt * 64 + lane], s = sink[tt * 64 + lane];
        float o1 = a * c - b * s, o2 = b * c + a * s;
        size_t oi = ((size_t)kh * 128 + tt) * 128;
        outk[oi + lane] = o1; outk[oi + lane + 64] = o2;   // output 1 (k), f32
        kb[oi + lane] = f2bf(o1); kb[oi + lane + 64] = f2bf(o2);
    } else {                                   // v: (kh, t) partial sum only
        int rr = wid - 3072;
        int kh = rr >> 7, tt = rr & 127;
        size_t ro = (size_t)tt * 6144 + 5120 + kh * 128;
        float v1 = 0.f, v2 = 0.f;
        #pragma unroll
        for (int s = 0; s < KSPLIT; s++) {
            v1 += part[(size_t)s * 786432 + ro + lane];
            v2 += part[(size_t)s * 786432 + ro + lane + 64];
        }
        size_t oi = ((size_t)kh * 128 + tt) * 128;
        outv[oi + lane] = v1; outv[oi + lane + 64] = v2;   // output 2 (v), f32
        vbw[oi + lane] = f2bf(v1); vbw[oi + lane + 64] = f2bf(v2);
    }
}

// --------- Kernel 3: split-K flash attention (no-max online softmax) --------
// grid (NSP, 8); each block handles NBLK kv-blocks of 64 keys (NSP*NBLK*64=4224).
template<int NSP, int NBLK>
__global__ __launch_bounds__(256)
void k_attn(const u16* __restrict__ qb, const u16* __restrict__ kbw,
            const u16* __restrict__ vbw,
            const float* __restrict__ cacheK, const float* __restrict__ cacheV,
            u16* __restrict__ opart, float* __restrict__ lpart)
{
    const int split = blockIdx.x;
    const int kh = blockIdx.y;
    const int t = threadIdx.x;
    const int w = t >> 6, l = t & 63;
    const int lm = l & 15, lg = l >> 4;

    __shared__ __align__(16) u16 Ks[64][136];
    __shared__ __align__(16) u16 Vs[128][72];
    __shared__ __align__(16) u16 Ps[4][64][40];

    const u16* qh = qb + ((size_t)(kh * 4 + w) * 64) * 128;
    bf16x8 aq[4][4];
    #pragma unroll
    for (int mt = 0; mt < 4; mt++)
        #pragma unroll
        for (int ks = 0; ks < 4; ks++)
            aq[mt][ks] = *(const bf16x8*)&qh[(size_t)(mt * 16 + lm) * 128 + ks * 32 + lg * 8];

    f32x4 accO[4][8] = {};
    float lacc[4][4] = {};
    const size_t khK = (size_t)kh * 8192 * 128;

    for (int kbi = 0; kbi < NBLK; kbi++) {
        const int key0 = split * (64 * NBLK) + kbi * 64;
        __syncthreads();
        #pragma unroll
        for (int it = 0; it < 8; it++) {
            int fidx = it * 256 + t;
            int row = fidx >> 5;
            int d4 = (fidx & 31) << 2;
            int key = key0 + row;
            if (key < 4096) {
                float4 kv = *(const float4*)&cacheK[khK + (size_t)key * 128 + d4];
                ushort4 sv; sv.x = f2bf(kv.x); sv.y = f2bf(kv.y);
                sv.z = f2bf(kv.z); sv.w = f2bf(kv.w);
                *(ushort4*)&Ks[row][d4] = sv;
                float4 vv = *(const float4*)&cacheV[khK + (size_t)key * 128 + d4];
                Vs[d4 + 0][row] = f2bf(vv.x);
                Vs[d4 + 1][row] = f2bf(vv.y);
                Vs[d4 + 2][row] = f2bf(vv.z);
                Vs[d4 + 3][row] = f2bf(vv.w);
            } else {
                size_t nb = ((size_t)kh * 128 + (key - 4096)) * 128 + d4;
                ushort4 kv = *(const ushort4*)&kbw[nb];
                *(ushort4*)&Ks[row][d4] = kv;
                ushort4 vv = *(const ushort4*)&vbw[nb];
                Vs[d4 + 0][row] = vv.x;
                Vs[d4 + 1][row] = vv.y;
                Vs[d4 + 2][row] = vv.z;
                Vs[d4 + 3][row] = vv.w;
            }
        }
        __syncthreads();

        f32x4 sa[4][4] = {};
        #pragma unroll
        for (int ks = 0; ks < 4; ks++) {
            bf16x8 bk[4];
            #pragma unroll
            for (int nt = 0; nt < 4; nt++)
                bk[nt] = *(const bf16x8*)&Ks[nt * 16 + lm][ks * 32 + lg * 8];
            #pragma unroll
            for (int mt = 0; mt < 4; mt++)
                #pragma unroll
                for (int nt = 0; nt < 4; nt++)
                    sa[mt][nt] = mfma16(aq[mt][ks], bk[nt], sa[mt][nt]);
        }

        #pragma unroll
        for (int half = 0; half < 2; half++) {
            __syncthreads();
            #pragma unroll
            for (int mt = 0; mt < 4; mt++)
                #pragma unroll
                for (int nt2 = 0; nt2 < 2; nt2++)
                    #pragma unroll
                    for (int r = 0; r < 4; r++) {
                        float e = __expf(sa[mt][half * 2 + nt2][r]);
                        lacc[mt][r] += e;
                        Ps[w][mt * 16 + lg * 4 + r][nt2 * 16 + lm] = f2bf(e);
                    }
            __syncthreads();
            bf16x8 pa[4];
            #pragma unroll
            for (int mt = 0; mt < 4; mt++)
                pa[mt] = *(const bf16x8*)&Ps[w][mt * 16 + lm][lg * 8];
            #pragma unroll
            for (int dt = 0; dt < 8; dt++) {
                bf16x8 vb8 = *(const bf16x8*)&Vs[dt * 16 + lm][half * 32 + lg * 8];
                #pragma unroll
                for (int mt = 0; mt < 4; mt++)
                    accO[mt][dt] = mfma16(pa[mt], vb8, accO[mt][dt]);
            }
        }
    }

    #pragma unroll
    for (int mt = 0; mt < 4; mt++)
        #pragma unroll
        for (int r = 0; r < 4; r++) {
            float v = lacc[mt][r];
            v += __shfl_xor(v, 1);
            v += __shfl_xor(v, 2);
            v += __shfl_xor(v, 4);
            v += __shfl_xor(v, 8);
            lacc[mt][r] = v;
        }

    const size_t base = (((size_t)kh * NSP + split) * 4 + w) * 64;
    if (lm == 0) {
        #pragma unroll
        for (int mt = 0; mt < 4; mt++)
            #pragma unroll
            for (int r = 0; r < 4; r++)
                lpart[base + mt * 16 + lg * 4 + r] = lacc[mt][r];
    }
    #pragma unroll
    for (int mt = 0; mt < 4; mt++)
        #pragma unroll
        for (int dt = 0; dt < 8; dt++)
            #pragma unroll
            for (int r = 0; r < 4; r++)
                opart[(base + mt * 16 + lg * 4 + r) * 128 + dt * 16 + lm] =
                    f2bf(accO[mt][dt][r]);
}

// ------------------- Kernel 4: combine splits, normalize --------------------
template<int NSP>
__global__ __launch_bounds__(256)
void k_combine(const u16* __restrict__ opart, const float* __restrict__ lpart,
               u16* __restrict__ obf)
{
    int idx = blockIdx.x * 256 + threadIdx.x;
    int lq = idx >> 12;
    int col = idx & 4095;
    int h = col >> 7, d = col & 127;
    int kh = h >> 2, rep = h & 3;
    float os = 0.f, ls = 0.f;
    #pragma unroll 4
    for (int s = 0; s < NSP; s++) {
        size_t b = (((size_t)kh * NSP + s) * 4 + rep) * 64 + lq;
        os += bf2f(opart[b * 128 + d]);
        ls += lpart[b];
    }
    obf[idx] = f2bf(os / ls);
}

// ----------- Kernel 5: O projection, split-K streaming (8 splits) -----------
__global__ __launch_bounds__(256)
void k_oproj(const u16* __restrict__ obf, const float* __restrict__ Wo,
             float* __restrict__ parto)
{
    const int col0 = blockIdx.x * 32;
    const int osp = blockIdx.y;
    const int ks0 = osp * (4096 / OSPLIT);

    __shared__ __align__(16) u16 As[64][72];
    __shared__ __align__(16) u16 Bs[32 * 64];

    const int t = threadIdx.x;
    const int w = t >> 6, l = t & 63;
    const int lm = l & 15, lg = l >> 4;

    const int arow = t >> 3;               // 0..31, +32 for second half
    const int ac8 = (t & 7) << 3;
    const int bk = (t >> 3) << 1;          // even k index (k-pair)
    const int bn4 = (t & 7) << 2;

    u16x8 pa[2]; f32x4 pb[2];
    f32x4 acc[2] = {};

    #define OP_LOAD(kt_)                                                       \
    {                                                                          \
        const int kg = ks0 + (kt_) * 64;                                       \
        pa[0] = *(const u16x8*)&obf[(size_t)arow * 4096 + kg + ac8];           \
        pa[1] = *(const u16x8*)&obf[(size_t)(arow + 32) * 4096 + kg + ac8];    \
        pb[0] = *(const f32x4*)&Wo[(size_t)(kg + bk) * 4096 + col0 + bn4];     \
        pb[1] = *(const f32x4*)&Wo[(size_t)(kg + bk + 1) * 4096 + col0 + bn4]; \
    }

    #define OP_STORE()                                                         \
    {                                                                          \
        *(u16x8*)&As[arow][ac8] = pa[0];                                       \
        *(u16x8*)&As[arow + 32][ac8] = pa[1];                                  \
        _Pragma("unroll")                                                      \
        for (int j = 0; j < 4; j++) {                                          \
            int n = bn4 + j;                                                   \
            int idx = n * 64 + (bk ^ (((n >> 1) & 7) << 3));                   \
            ushort2 v2; v2.x = f2bf(pb[0][j]); v2.y = f2bf(pb[1][j]);          \
            *(ushort2*)&Bs[idx] = v2;                                          \
        }                                                                      \
    }

    OP_LOAD(0);
    #pragma unroll 1
    for (int kt = 0; kt < 4096 / OSPLIT / 64; kt++) {
        if (kt) __syncthreads();
        OP_STORE();
        __syncthreads();
        if (kt + 1 < 4096 / OSPLIT / 64) OP_LOAD(kt + 1);
        #pragma unroll
        for (int ks = 0; ks < 2; ks++) {
            const int koff = ks * 32 + lg * 8;
            bf16x8 a0 = *(const bf16x8*)&As[w * 16 + lm][koff];
            #pragma unroll
            for (int nt = 0; nt < 2; nt++) {
                int n = nt * 16 + lm;
                bf16x8 b = *(const bf16x8*)&Bs[n * 64 + (koff ^ (((n >> 1) & 7) << 3))];
                acc[nt] = mfma16(a0, b, acc[nt]);
            }
        }
    }
    #pragma unroll
    for (int nt = 0; nt < 2; nt++)
        #pragma unroll
        for (int r = 0; r < 4; r++)
            parto[((size_t)osp * 64 + w * 16 + lg * 4 + r) * 4096 +
                  col0 + nt * 16 + lm] = acc[nt][r];
    #undef OP_LOAD
    #undef OP_STORE
}

// ------------------- Kernel 6: sum O-proj split-K partials ------------------
__global__ __launch_bounds__(256)
void k_osum(const float* __restrict__ parto, float* __restrict__ out0)
{
    int idx = blockIdx.x * 256 + threadIdx.x;   // 64*4096
    float s = 0.f;
    #pragma unroll
    for (int o = 0; o < OSPLIT; o++)
        s += parto[(size_t)o * 262144 + idx];
    out0[idx] = s;
}

extern "C" void kernel_launch(void* const* d_in, const int* in_sizes, int n_in,
                              void* d_out, int out_size, void* d_ws, size_t ws_size,
                              hipStream_t stream)
{
    (void)in_sizes; (void)n_in; (void)out_size;
    const float* x      = (const float*)d_in[0];
    const float* xctx   = (const float*)d_in[1];
    const float* cosq   = (const float*)d_in[2];
    const float* sinq   = (const float*)d_in[3];
    const float* cosk   = (const float*)d_in[4];
    const float* sink   = (const float*)d_in[5];
    const float* cacheK = (const float*)d_in[6];
    const float* cacheV = (const float*)d_in[7];
    const float* Wq     = (const float*)d_in[9];
    const float* Wk     = (const float*)d_in[10];
    const float* Wv     = (const float*)d_in[11];
    const float* Wo     = (const float*)d_in[12];
    const float* qnw    = (const float*)d_in[13];
    const float* knw    = (const float*)d_in[14];

    float* out0 = (float*)d_out;               // o@Wo (64, 4096)
    float* out1 = out0 + 262144;               // k (8, 128, 128)
    float* out2 = out1 + 131072;               // v (8, 128, 128)

    // BIG path (attention NSPLIT=66, 528 blocks = 2.06/CU) needs:
    //   opart 34,603,008 + lpart 540,672 + region B 1,572,864 = 36,716,544.
    // SMALL fallback (NSPLIT=22, proven R3/R5 layout) = 14,155,776.
    const bool big = (ws_size >= 36716544ull);
    char* ws = (char*)d_ws;
    const size_t lpart_off = big ? 34603008ull : 11534336ull;
    const size_t regB      = big ? 35143680ull : 12582912ull;

    float* part  = (float*)(ws + 0);           // phase 1-2
    u16*   opart = (u16*)(ws + 0);             // phase 3-4 (aliases dead part)
    float* lpart = (float*)(ws + lpart_off);
    float* parto = (float*)(ws + 0);           // phase 5-6 (aliases dead opart)
    u16*   fragA = (u16*)(ws + regB);          // 1 MB, aliases qb/kb/vb (phases 0-1)
    u16*   qb    = (u16*)(ws + regB);
    u16*   kb    = (u16*)(ws + regB + 524288);
    u16*   vb    = (u16*)(ws + regB + 786432);
    u16*   obf   = (u16*)(ws + regB + 1048576);

    k_prep<<<256, 256, 0, stream>>>(x, xctx, fragA);
    k_qkv<<<dim3(384, KSPLIT), 256, 0, stream>>>(fragA, Wq, Wk, Wv, part);
    k_normrope<<<1024, 256, 0, stream>>>(part, cosq, sinq, cosk, sink,
                                         qnw, knw, qb, kb, out1, out2, vb);
    if (big) {
        k_attn<66, 1><<<dim3(66, 8), 256, 0, stream>>>(qb, kb, vb, cacheK, cacheV,
                                                       opart, lpart);
        k_combine<66><<<1024, 256, 0, stream>>>(opart, lpart, obf);
    } else {
        k_attn<22, 3><<<dim3(22, 8), 256, 0, stream>>>(qb, kb, vb, cacheK, cacheV,
                                                       opart, lpart);
        k_combine<22><<<1024, 256, 0, stream>>>(opart, lpart, obf);
    }
    k_oproj<<<dim3(128, OSPLIT), 256, 0, stream>>>(obf, Wo, parto);
    k_osum<<<1024, 256, 0, stream>>>(parto, out0);
}

// Round 7
// 89.545 us; speedup vs baseline: 1.3360x; 1.3360x over previous
//
#include <hip/hip_runtime.h>

typedef unsigned short u16;
typedef __bf16 bf16x8 __attribute__((ext_vector_type(8)));
typedef float f32x4 __attribute__((ext_vector_type(4)));
typedef u16 u16x8 __attribute__((ext_vector_type(8)));

#define NSPLIT 22            // attention: 4224 keys = 22 * 192
#define OSPLIT 8             // oproj K-splits (512 each, 8 steps of 64)
#define SCALE_Q 0.08838834764831843f   // 1/sqrt(128), folded into q

__device__ __forceinline__ u16 f2bf(float f) {
    unsigned u = __builtin_bit_cast(unsigned, f);
    u += 0x7fff + ((u >> 16) & 1);     // RNE
    return (u16)(u >> 16);
}
__device__ __forceinline__ float bf2f(u16 h) {
    unsigned u = ((unsigned)h) << 16;
    return __builtin_bit_cast(float, u);
}
__device__ __forceinline__ f32x4 mfma16(bf16x8 a, bf16x8 b, f32x4 c) {
    return __builtin_amdgcn_mfma_f32_16x16x32_bf16(a, b, c, 0, 0, 0);
}

// ------ Kernel 0: pre-pack c=[x_ctx;x] as bf16 MFMA A-fragments (1 MB) ------
// fragA[((ks32*8 + rt)*64 + l)*8 + e] = bf16(c[rt*16 + (l&15)][ks32*32 + (l>>4)*8 + e])
__global__ __launch_bounds__(256)
void k_prep(const float* __restrict__ x, const float* __restrict__ xctx,
            u16* __restrict__ fragA)
{
    int tid = blockIdx.x * 256 + threadIdx.x;   // 65536 threads
    int row = tid >> 9;                         // 0..127
    int kc = tid & 511;                         // k-chunk of 8
    int k0 = kc << 3;
    const float* src = (row < 64) ? (xctx + (size_t)row * 4096)
                                  : (x + (size_t)(row - 64) * 4096);
    f32x4 v0 = *(const f32x4*)&src[k0];
    f32x4 v1 = *(const f32x4*)&src[k0 + 4];
    u16x8 o;
    o[0] = f2bf(v0[0]); o[1] = f2bf(v0[1]); o[2] = f2bf(v0[2]); o[3] = f2bf(v0[3]);
    o[4] = f2bf(v1[0]); o[5] = f2bf(v1[1]); o[6] = f2bf(v1[2]); o[7] = f2bf(v1[3]);
    int ks32 = k0 >> 5;
    int lg = (k0 >> 3) & 3;
    int rt = row >> 4;
    int l = lg * 16 + (row & 15);
    *(u16x8*)&fragA[(((size_t)ks32 * 8 + rt) * 64 + l) * 8] = o;
}

// ---------------- Kernel 1: QKV projection, split-K streaming ---------------
// grid (192, KS): x = 32-col tile over [Wq(4096)|Wk(1024)|Wv(1024)],
// y = K-split of 4096/KS. A from fragA (global->reg, no LDS); B staged in
// 4 KB swizzled LDS. Writes f32 partials part[ksp][128][6144].
template<int KS>
__global__ __launch_bounds__(256)
void k_qkv(const u16* __restrict__ fragA,
           const float* __restrict__ Wq, const float* __restrict__ Wk,
           const float* __restrict__ Wv, float* __restrict__ part)
{
    constexpr int KCk = 4096 / KS;
    constexpr int NKTk = KCk / 64;
    const int col0 = blockIdx.x * 32;
    const int ksp = blockIdx.y;
    const int ks0 = ksp * KCk;
    const float* W; int ldw, cbase, mat;
    if (col0 < 4096)      { W = Wq; ldw = 4096; cbase = col0;        mat = 0; }
    else if (col0 < 5120) { W = Wk; ldw = 1024; cbase = col0 - 4096; mat = 1; }
    else                  { W = Wv; ldw = 1024; cbase = col0 - 5120; mat = 2; }
    const bool full = (mat != 0);          // k/v need all 128 rows; q only x rows
    const int rowbase = full ? 0 : 64;

    __shared__ __align__(16) u16 Bs[32 * 64];   // [n][k] with XOR swizzle, 4KB

    const int t = threadIdx.x;
    const int w = t >> 6, l = t & 63;
    const int lm = l & 15, lg = l >> 4;

    const int bk = (t >> 3) << 1;          // even k index (k-pair)
    const int bn4 = (t & 7) << 2;          // col group of 4

    f32x4 pb[2];
    f32x4 acc[2][2] = {};

    const int rt0 = full ? (w * 2) : (4 + w);  // A row-tile(s) for this wave

    #define QKV_BLOAD(kt_)                                                     \
    {                                                                          \
        const int kg = ks0 + (kt_) * 64;                                       \
        pb[0] = *(const f32x4*)&W[(size_t)(kg + bk) * ldw + cbase + bn4];      \
        pb[1] = *(const f32x4*)&W[(size_t)(kg + bk + 1) * ldw + cbase + bn4];  \
    }

    #define QKV_BSTORE()                                                       \
    {                                                                          \
        _Pragma("unroll")                                                      \
        for (int j = 0; j < 4; j++) {                                          \
            int n = bn4 + j;                                                   \
            int idx = n * 64 + (bk ^ (((n >> 1) & 7) << 3));                   \
            ushort2 v2; v2.x = f2bf(pb[0][j]); v2.y = f2bf(pb[1][j]);          \
            *(ushort2*)&Bs[idx] = v2;                                          \
        }                                                                      \
    }

    QKV_BLOAD(0);
    #pragma unroll 1
    for (int kt = 0; kt < NKTk; kt++) {
        if (kt) __syncthreads();           // prev tile's readers done
        QKV_BSTORE();
        __syncthreads();
        if (kt + 1 < NKTk) QKV_BLOAD(kt + 1);
        const int ks32b = (ks0 >> 5) + kt * 2;
        #pragma unroll
        for (int ks = 0; ks < 2; ks++) {
            const int koff = ks * 32 + lg * 8;
            bf16x8 bfr[2];
            #pragma unroll
            for (int nt = 0; nt < 2; nt++) {
                int n = nt * 16 + lm;
                bfr[nt] = *(const bf16x8*)&Bs[n * 64 + (koff ^ (((n >> 1) & 7) << 3))];
            }
            bf16x8 a0 = *(const bf16x8*)
                &fragA[(((size_t)(ks32b + ks) * 8 + rt0) * 64 + l) * 8];
            acc[0][0] = mfma16(a0, bfr[0], acc[0][0]);
            acc[0][1] = mfma16(a0, bfr[1], acc[0][1]);
            if (full) {
                bf16x8 a1 = *(const bf16x8*)
                    &fragA[(((size_t)(ks32b + ks) * 8 + rt0 + 1) * 64 + l) * 8];
                acc[1][0] = mfma16(a1, bfr[0], acc[1][0]);
                acc[1][1] = mfma16(a1, bfr[1], acc[1][1]);
            }
        }
    }

    const int wrows = full ? 32 : 16;
    const int mts = full ? 2 : 1;
    #pragma unroll
    for (int mt = 0; mt < 2; mt++) {
        if (mt >= mts) break;
        #pragma unroll
        for (int nt = 0; nt < 2; nt++)
            #pragma unroll
            for (int r = 0; r < 4; r++) {
                int grow = rowbase + w * wrows + mt * 16 + lg * 4 + r;
                part[((size_t)ksp * 128 + grow) * 6144 + col0 + nt * 16 + lm] =
                    acc[mt][nt][r];
            }
    }
    #undef QKV_BLOAD
    #undef QKV_BSTORE
}

// ------- Kernel 2: partial-sum + RMSNorm + RoPE (q, k) + v passthrough ------
template<int KS>
__global__ __launch_bounds__(256)
void k_normrope(const float* __restrict__ part,
                const float* __restrict__ cosq, const float* __restrict__ sinq,
                const float* __restrict__ cosk, const float* __restrict__ sink,
                const float* __restrict__ qnw, const float* __restrict__ knw,
                u16* __restrict__ qb, u16* __restrict__ kb,
                float* __restrict__ outk, float* __restrict__ outv,
                u16* __restrict__ vbw)
{
    int wid = blockIdx.x * 4 + (threadIdx.x >> 6);
    int lane = threadIdx.x & 63;
    if (wid < 2048) {                          // q: (h, l)
        int h = wid >> 6, lq = wid & 63;
        size_t ro = (size_t)(64 + lq) * 6144 + h * 128;
        float x1 = 0.f, x2 = 0.f;
        #pragma unroll
        for (int s = 0; s < KS; s++) {
            x1 += part[(size_t)s * 786432 + ro + lane];
            x2 += part[(size_t)s * 786432 + ro + lane + 64];
        }
        float ss = x1 * x1 + x2 * x2;
        #pragma unroll
        for (int off = 32; off; off >>= 1) ss += __shfl_xor(ss, off);
        float rms = rsqrtf(ss * (1.0f / 128.0f) + 1e-6f);
        float a = x1 * rms * qnw[lane];
        float b = x2 * rms * qnw[lane + 64];
        float c = cosq[lq * 64 + lane], s = sinq[lq * 64 + lane];
        u16* qo = qb + ((size_t)h * 64 + lq) * 128;
        qo[lane]      = f2bf((a * c - b * s) * SCALE_Q);
        qo[lane + 64] = f2bf((b * c + a * s) * SCALE_Q);
    } else if (wid < 3072) {                   // k: (kh, t)
        int rr = wid - 2048;
        int kh = rr >> 7, tt = rr & 127;
        size_t ro = (size_t)tt * 6144 + 4096 + kh * 128;
        float x1 = 0.f, x2 = 0.f;
        #pragma unroll
        for (int s = 0; s < KS; s++) {
            x1 += part[(size_t)s * 786432 + ro + lane];
            x2 += part[(size_t)s * 786432 + ro + lane + 64];
        }
        float ss = x1 * x1 + x2 * x2;
        #pragma unroll
        for (int off = 32; off; off >>= 1) ss += __shfl_xor(ss, off);
        float rms = rsqrtf(ss * (1.0f / 128.0f) + 1e-6f);
        float a = x1 * rms * knw[lane];
        float b = x2 * rms * knw[lane + 64];
        float c = cosk[tt * 64 + lane], s = sink[tt * 64 + lane];
        float o1 = a * c - b * s, o2 = b * c + a * s;
        size_t oi = ((size_t)kh * 128 + tt) * 128;
        outk[oi + lane] = o1; outk[oi + lane + 64] = o2;   // output 1 (k), f32
        kb[oi + lane] = f2bf(o1); kb[oi + lane + 64] = f2bf(o2);
    } else {                                   // v: (kh, t) partial sum only
        int rr = wid - 3072;
        int kh = rr >> 7, tt = rr & 127;
        size_t ro = (size_t)tt * 6144 + 5120 + kh * 128;
        float v1 = 0.f, v2 = 0.f;
        #pragma unroll
        for (int s = 0; s < KS; s++) {
            v1 += part[(size_t)s * 786432 + ro + lane];
            v2 += part[(size_t)s * 786432 + ro + lane + 64];
        }
        size_t oi = ((size_t)kh * 128 + tt) * 128;
        outv[oi + lane] = v1; outv[oi + lane + 64] = v2;   // output 2 (v), f32
        vbw[oi + lane] = f2bf(v1); vbw[oi + lane + 64] = f2bf(v2);
    }
}

// --------- Kernel 3: split-K flash attention (no-max online softmax) --------
// grid (NSP, 8); each block handles NBLK kv-blocks of 64 keys.
template<int NSP, int NBLK>
__global__ __launch_bounds__(256)
void k_attn(const u16* __restrict__ qb, const u16* __restrict__ kbw,
            const u16* __restrict__ vbw,
            const float* __restrict__ cacheK, const float* __restrict__ cacheV,
            u16* __restrict__ opart, float* __restrict__ lpart)
{
    const int split = blockIdx.x;
    const int kh = blockIdx.y;
    const int t = threadIdx.x;
    const int w = t >> 6, l = t & 63;
    const int lm = l & 15, lg = l >> 4;

    __shared__ __align__(16) u16 Ks[64][136];
    __shared__ __align__(16) u16 Vs[128][72];
    __shared__ __align__(16) u16 Ps[4][64][40];

    const u16* qh = qb + ((size_t)(kh * 4 + w) * 64) * 128;
    bf16x8 aq[4][4];
    #pragma unroll
    for (int mt = 0; mt < 4; mt++)
        #pragma unroll
        for (int ks = 0; ks < 4; ks++)
            aq[mt][ks] = *(const bf16x8*)&qh[(size_t)(mt * 16 + lm) * 128 + ks * 32 + lg * 8];

    f32x4 accO[4][8] = {};
    float lacc[4][4] = {};
    const size_t khK = (size_t)kh * 8192 * 128;

    for (int kbi = 0; kbi < NBLK; kbi++) {
        const int key0 = split * (64 * NBLK) + kbi * 64;
        __syncthreads();
        #pragma unroll
        for (int it = 0; it < 8; it++) {
            int fidx = it * 256 + t;
            int row = fidx >> 5;
            int d4 = (fidx & 31) << 2;
            int key = key0 + row;
            if (key < 4096) {
                float4 kv = *(const float4*)&cacheK[khK + (size_t)key * 128 + d4];
                ushort4 sv; sv.x = f2bf(kv.x); sv.y = f2bf(kv.y);
                sv.z = f2bf(kv.z); sv.w = f2bf(kv.w);
                *(ushort4*)&Ks[row][d4] = sv;
                float4 vv = *(const float4*)&cacheV[khK + (size_t)key * 128 + d4];
                Vs[d4 + 0][row] = f2bf(vv.x);
                Vs[d4 + 1][row] = f2bf(vv.y);
                Vs[d4 + 2][row] = f2bf(vv.z);
                Vs[d4 + 3][row] = f2bf(vv.w);
            } else {
                size_t nb = ((size_t)kh * 128 + (key - 4096)) * 128 + d4;
                ushort4 kv = *(const ushort4*)&kbw[nb];
                *(ushort4*)&Ks[row][d4] = kv;
                ushort4 vv = *(const ushort4*)&vbw[nb];
                Vs[d4 + 0][row] = vv.x;
                Vs[d4 + 1][row] = vv.y;
                Vs[d4 + 2][row] = vv.z;
                Vs[d4 + 3][row] = vv.w;
            }
        }
        __syncthreads();

        f32x4 sa[4][4] = {};
        #pragma unroll
        for (int ks = 0; ks < 4; ks++) {
            bf16x8 bk[4];
            #pragma unroll
            for (int nt = 0; nt < 4; nt++)
                bk[nt] = *(const bf16x8*)&Ks[nt * 16 + lm][ks * 32 + lg * 8];
            #pragma unroll
            for (int mt = 0; mt < 4; mt++)
                #pragma unroll
                for (int nt = 0; nt < 4; nt++)
                    sa[mt][nt] = mfma16(aq[mt][ks], bk[nt], sa[mt][nt]);
        }

        #pragma unroll
        for (int half = 0; half < 2; half++) {
            __syncthreads();
            #pragma unroll
            for (int mt = 0; mt < 4; mt++)
                #pragma unroll
                for (int nt2 = 0; nt2 < 2; nt2++)
                    #pragma unroll
                    for (int r = 0; r < 4; r++) {
                        float e = __expf(sa[mt][half * 2 + nt2][r]);
                        lacc[mt][r] += e;
                        Ps[w][mt * 16 + lg * 4 + r][nt2 * 16 + lm] = f2bf(e);
                    }
            __syncthreads();
            bf16x8 pa[4];
            #pragma unroll
            for (int mt = 0; mt < 4; mt++)
                pa[mt] = *(const bf16x8*)&Ps[w][mt * 16 + lm][lg * 8];
            #pragma unroll
            for (int dt = 0; dt < 8; dt++) {
                bf16x8 vb8 = *(const bf16x8*)&Vs[dt * 16 + lm][half * 32 + lg * 8];
                #pragma unroll
                for (int mt = 0; mt < 4; mt++)
                    accO[mt][dt] = mfma16(pa[mt], vb8, accO[mt][dt]);
            }
        }
    }

    #pragma unroll
    for (int mt = 0; mt < 4; mt++)
        #pragma unroll
        for (int r = 0; r < 4; r++) {
            float v = lacc[mt][r];
            v += __shfl_xor(v, 1);
            v += __shfl_xor(v, 2);
            v += __shfl_xor(v, 4);
            v += __shfl_xor(v, 8);
            lacc[mt][r] = v;
        }

    const size_t base = (((size_t)kh * NSP + split) * 4 + w) * 64;
    if (lm == 0) {
        #pragma unroll
        for (int mt = 0; mt < 4; mt++)
            #pragma unroll
            for (int r = 0; r < 4; r++)
                lpart[base + mt * 16 + lg * 4 + r] = lacc[mt][r];
    }
    #pragma unroll
    for (int mt = 0; mt < 4; mt++)
        #pragma unroll
        for (int dt = 0; dt < 8; dt++)
            #pragma unroll
            for (int r = 0; r < 4; r++)
                opart[(base + mt * 16 + lg * 4 + r) * 128 + dt * 16 + lm] =
                    f2bf(accO[mt][dt][r]);
}

// ---------- Kernel 4: combine splits, normalize (vectorized u16x8) ----------
template<int NSP>
__global__ __launch_bounds__(256)
void k_combine(const u16* __restrict__ opart, const float* __restrict__ lpart,
               u16* __restrict__ obf)
{
    int idx = blockIdx.x * 256 + threadIdx.x;   // 32768 threads: (lq, col/8)
    int lq = idx >> 9;
    int c8 = (idx & 511) << 3;                  // 8-col group (within one head)
    int h = c8 >> 7, d = c8 & 127;
    int kh = h >> 2, rep = h & 3;
    float os[8] = {};
    float ls = 0.f;
    #pragma unroll 2
    for (int s = 0; s < NSP; s++) {
        size_t b = (((size_t)kh * NSP + s) * 4 + rep) * 64 + lq;
        u16x8 v = *(const u16x8*)&opart[b * 128 + d];
        #pragma unroll
        for (int j = 0; j < 8; j++) os[j] += bf2f(v[j]);
        ls += lpart[b];
    }
    float inv = 1.0f / ls;
    u16x8 o;
    #pragma unroll
    for (int j = 0; j < 8; j++) o[j] = f2bf(os[j] * inv);
    *(u16x8*)&obf[(size_t)lq * 4096 + c8] = o;
}

// ----------- Kernel 5: O projection, split-K streaming (8 splits) -----------
__global__ __launch_bounds__(256)
void k_oproj(const u16* __restrict__ obf, const float* __restrict__ Wo,
             float* __restrict__ parto)
{
    const int col0 = blockIdx.x * 32;
    const int osp = blockIdx.y;
    const int ks0 = osp * (4096 / OSPLIT);

    __shared__ __align__(16) u16 As[64][72];
    __shared__ __align__(16) u16 Bs[32 * 64];

    const int t = threadIdx.x;
    const int w = t >> 6, l = t & 63;
    const int lm = l & 15, lg = l >> 4;

    const int arow = t >> 3;               // 0..31, +32 for second half
    const int ac8 = (t & 7) << 3;
    const int bk = (t >> 3) << 1;          // even k index (k-pair)
    const int bn4 = (t & 7) << 2;

    u16x8 pa[2]; f32x4 pb[2];
    f32x4 acc[2] = {};

    #define OP_LOAD(kt_)                                                       \
    {                                                                          \
        const int kg = ks0 + (kt_) * 64;                                       \
        pa[0] = *(const u16x8*)&obf[(size_t)arow * 4096 + kg + ac8];           \
        pa[1] = *(const u16x8*)&obf[(size_t)(arow + 32) * 4096 + kg + ac8];    \
        pb[0] = *(const f32x4*)&Wo[(size_t)(kg + bk) * 4096 + col0 + bn4];     \
        pb[1] = *(const f32x4*)&Wo[(size_t)(kg + bk + 1) * 4096 + col0 + bn4]; \
    }

    #define OP_STORE()                                                         \
    {                                                                          \
        *(u16x8*)&As[arow][ac8] = pa[0];                                       \
        *(u16x8*)&As[arow + 32][ac8] = pa[1];                                  \
        _Pragma("unroll")                                                      \
        for (int j = 0; j < 4; j++) {                                          \
            int n = bn4 + j;                                                   \
            int idx = n * 64 + (bk ^ (((n >> 1) & 7) << 3));                   \
            ushort2 v2; v2.x = f2bf(pb[0][j]); v2.y = f2bf(pb[1][j]);          \
            *(ushort2*)&Bs[idx] = v2;                                          \
        }                                                                      \
    }

    OP_LOAD(0);
    #pragma unroll 1
    for (int kt = 0; kt < 4096 / OSPLIT / 64; kt++) {
        if (kt) __syncthreads();
        OP_STORE();
        __syncthreads();
        if (kt + 1 < 4096 / OSPLIT / 64) OP_LOAD(kt + 1);
        #pragma unroll
        for (int ks = 0; ks < 2; ks++) {
            const int koff = ks * 32 + lg * 8;
            bf16x8 a0 = *(const bf16x8*)&As[w * 16 + lm][koff];
            #pragma unroll
            for (int nt = 0; nt < 2; nt++) {
                int n = nt * 16 + lm;
                bf16x8 b = *(const bf16x8*)&Bs[n * 64 + (koff ^ (((n >> 1) & 7) << 3))];
                acc[nt] = mfma16(a0, b, acc[nt]);
            }
        }
    }
    #pragma unroll
    for (int nt = 0; nt < 2; nt++)
        #pragma unroll
        for (int r = 0; r < 4; r++)
            parto[((size_t)osp * 64 + w * 16 + lg * 4 + r) * 4096 +
                  col0 + nt * 16 + lm] = acc[nt][r];
    #undef OP_LOAD
    #undef OP_STORE
}

// ------------------- Kernel 6: sum O-proj split-K partials ------------------
__global__ __launch_bounds__(256)
void k_osum(const float* __restrict__ parto, float* __restrict__ out0)
{
    int idx = blockIdx.x * 256 + threadIdx.x;   // 64*4096
    float s = 0.f;
    #pragma unroll
    for (int o = 0; o < OSPLIT; o++)
        s += parto[(size_t)o * 262144 + idx];
    out0[idx] = s;
}

extern "C" void kernel_launch(void* const* d_in, const int* in_sizes, int n_in,
                              void* d_out, int out_size, void* d_ws, size_t ws_size,
                              hipStream_t stream)
{
    (void)in_sizes; (void)n_in; (void)out_size;
    const float* x      = (const float*)d_in[0];
    const float* xctx   = (const float*)d_in[1];
    const float* cosq   = (const float*)d_in[2];
    const float* sinq   = (const float*)d_in[3];
    const float* cosk   = (const float*)d_in[4];
    const float* sink   = (const float*)d_in[5];
    const float* cacheK = (const float*)d_in[6];
    const float* cacheV = (const float*)d_in[7];
    const float* Wq     = (const float*)d_in[9];
    const float* Wk     = (const float*)d_in[10];
    const float* Wv     = (const float*)d_in[11];
    const float* Wo     = (const float*)d_in[12];
    const float* qnw    = (const float*)d_in[13];
    const float* knw    = (const float*)d_in[14];

    float* out0 = (float*)d_out;               // o@Wo (64, 4096)
    float* out1 = out0 + 262144;               // k (8, 128, 128)
    float* out2 = out1 + 131072;               // v (8, 128, 128)

    // KSPLIT=8 layout needs: part 8x128x6144 f32 = 25,165,824 (region A; also
    // hosts opart 11,534,336 + lpart and parto 8,388,608 as later tenants)
    // + region B 1,572,864  ->  26,738,688 total.
    // R6 proved ws_size >= 36,716,544 (BIG branch ran), so this fits; a
    // KSPLIT=4 fallback (proven R5 layout, 14,155,776) guards anyway.
    const bool ks8 = (ws_size >= 26738688ull);
    char* ws = (char*)d_ws;
    const size_t regB = ks8 ? 25165824ull : 12582912ull;

    float* part  = (float*)(ws + 0);           // phase 1-2
    u16*   opart = (u16*)(ws + 0);             // phase 3-4 (aliases dead part)
    float* lpart = (float*)(ws + 11534336);
    float* parto = (float*)(ws + 0);           // phase 5-6 (aliases dead opart)
    u16*   fragA = (u16*)(ws + regB);          // 1 MB, aliases qb/kb/vb (phases 0-1)
    u16*   qb    = (u16*)(ws + regB);
    u16*   kb    = (u16*)(ws + regB + 524288);
    u16*   vb    = (u16*)(ws + regB + 786432);
    u16*   obf   = (u16*)(ws + regB + 1048576);

    k_prep<<<256, 256, 0, stream>>>(x, xctx, fragA);
    if (ks8) {
        k_qkv<8><<<dim3(192, 8), 256, 0, stream>>>(fragA, Wq, Wk, Wv, part);
        k_normrope<8><<<1024, 256, 0, stream>>>(part, cosq, sinq, cosk, sink,
                                                qnw, knw, qb, kb, out1, out2, vb);
    } else {
        k_qkv<4><<<dim3(192, 4), 256, 0, stream>>>(fragA, Wq, Wk, Wv, part);
        k_normrope<4><<<1024, 256, 0, stream>>>(part, cosq, sinq, cosk, sink,
                                                qnw, knw, qb, kb, out1, out2, vb);
    }
    k_attn<NSPLIT, 3><<<dim3(NSPLIT, 8), 256, 0, stream>>>(qb, kb, vb,
                                                           cacheK, cacheV,
                                                           opart, lpart);
    k_combine<NSPLIT><<<128, 256, 0, stream>>>(opart, lpart, obf);
    k_oproj<<<dim3(128, OSPLIT), 256, 0, stream>>>(obf, Wo, parto);
    k_osum<<<1024, 256, 0, stream>>>(parto, out0);
}